// Round 6
// baseline (302.145 us; speedup 1.0000x reference)
//
#include <hip/hip_runtime.h>

typedef __bf16 bf16x8 __attribute__((ext_vector_type(8)));
typedef float  f32x4  __attribute__((ext_vector_type(4)));

__device__ __forceinline__ unsigned short f2bf(float f) {
  unsigned u = __float_as_uint(f);
  u += 0x7FFFu + ((u >> 16) & 1u);   // round-to-nearest-even
  return (unsigned short)(u >> 16);
}

__device__ __forceinline__ unsigned cvtpk(float lo, float hi) {
  unsigned r;
  asm("v_cvt_pk_bf16_f32 %0, %1, %2" : "=v"(r) : "v"(lo), "v"(hi));
  return r;
}

#define WF_BYTES 147456  // 9 taps * 2 ci-chunks * 8 cout-blocks * 64 lanes * 16 B

// ---- weight transform: W[128][64][3][3] f32 -> bf16 MFMA B-fragment layout
// wf[(((kh*3+kw)*2+ck)*8+nb)*64 + lane][j] = W[nb*16+(lane&15)][ck*32+(lane>>4)*8+j][kh][kw]
__global__ __launch_bounds__(64) void wxf_746(const float* __restrict__ w,
                                              unsigned short* __restrict__ wf) {
  const int b = blockIdx.x;            // 0..143
  const int lane = threadIdx.x;        // 0..63
  const int nb = b & 7, ck = (b >> 3) & 1, pos = b >> 4;
  const int kh = pos / 3, kw = pos % 3;
  const int co = nb * 16 + (lane & 15);
  const int ci0 = ck * 32 + ((lane >> 4) << 3);
  unsigned short* o = wf + ((size_t)(b * 64 + lane) << 3);
#pragma unroll
  for (int j = 0; j < 8; ++j)
    o[j] = f2bf(w[((co * 64 + ci0 + j) * 3 + kh) * 3 + kw]);
}

// ---- persistent strip kernel: fused conv3x3+bias+relu+maxpool2x2, bf16 MFMA
// WG = (n, w-half, strip of 7 hpairs). 256 thr / 4 waves (wr = conv row, wh = cout half),
// acc[NF][4]. 6-slot LDS ring of input rows (slot = local_row % 6): step s computes slots
// (2s..2s+3)%6 while staging local rows 2s+4,2s+5 -> slots (2s+4,2s+5)%6 (disjoint).
// T14 split: next-row global loads issued BEFORE the MFMA loop, cvt+ds_write after.
// LDS ring: [6 slots][NCOLS][64 ci] bf16; byte = sl*ROWB + lc*128 + ((ci/8 ^ (lc&7))<<4) + (ci%8)*2
template<int NF, int WLO, int PWB>
__device__ __forceinline__ void strip_run(
    unsigned char* __restrict__ lds, const float* __restrict__ xn,
    const unsigned char* __restrict__ wsb, const float* __restrict__ bias,
    float* __restrict__ out, int n, int strip, int tid) {
  constexpr int NCOLS = NF * 16 + 2;
  constexpr int ROWB  = NCOLS * 128;
  constexpr int NQ    = NF * 4;          // float4 quads per (row, ci-pair)
  constexpr int NT    = NQ / 4;          // main staging tasks per thread
  constexpr int PWN   = NF * 8;
  constexpr int PWNP  = PWN + 4;
  constexpr int ZLC   = (WLO < 0) ? 0 : (NCOLS - 1);  // always-zero edge col
  constexpr int RLC   = (WLO < 0) ? (NCOLS - 1) : 0;  // real-data edge col

  const int lane = tid & 63, wid = tid >> 6;
  const int wr = wid >> 1, wh = wid & 1;   // wave conv-row (0/1), cout half (0/1)
  const int lw = lane & 15, hq = lane >> 4;
  float* pb = (float*)(lds + 6 * ROWB);

  float bb[4];
#pragma unroll
  for (int nf = 0; nf < 4; ++nf) bb[nf] = bias[wh * 64 + nf * 16 + lw];

  const f32x4 z4 = {0.f, 0.f, 0.f, 0.f};
  const int habs0 = strip * 14 - 1;        // abs conv row of local row 0

  // zero the always-out-of-image edge column in all 6 slots (stays zero)
  if (tid < 48) {
    const int sl = tid >> 3, q = tid & 7;
    *(f32x4*)&lds[sl * ROWB + ZLC * 128 + q * 16] = z4;
  }

  // --- staging helpers (load fills regs; write converts + scatters to ring) ---
  auto stage_load = [&](int lr0, f32x4 (*sa)[2], float& se0, float& se1) {
#pragma unroll
    for (int i = 0; i < NT; ++i) {
      const int idx = i * 256 + tid;
      const int w4 = idx % NQ;
      const int t  = idx / NQ;             // 0..63
      const int cip = t & 31, r = t >> 5;
      const int h = habs0 + lr0 + r;
      sa[i][0] = z4; sa[i][1] = z4;
      if ((unsigned)h < 112u) {
        const float* p = xn + (size_t)(cip * 2) * 12544 + h * 112 + (WLO + 1 + w4 * 4);
        sa[i][0] = *(const f32x4*)p;
        sa[i][1] = *(const f32x4*)(p + 12544);
      }
    }
    se0 = 0.f; se1 = 0.f;
    if (tid < 64) {
      const int cip = tid & 31, r = tid >> 5;
      const int h = habs0 + lr0 + r;
      if ((unsigned)h < 112u) {
        const float* p = xn + (size_t)(cip * 2) * 12544 + h * 112 + (WLO + RLC);
        se0 = p[0]; se1 = p[12544];
      }
    }
  };
  auto stage_write = [&](int lr0, const f32x4 (*sa)[2], float se0, float se1) {
#pragma unroll
    for (int i = 0; i < NT; ++i) {
      const int idx = i * 256 + tid;
      const int w4 = idx % NQ;
      const int t  = idx / NQ;
      const int cip = t & 31, r = t >> 5;
      const int sl = (lr0 + r) % 6;
      const int rb = sl * ROWB + (cip & 3) * 4;
      const int ch = cip >> 2;
#pragma unroll
      for (int q = 0; q < 4; ++q) {
        const int qe = (q + w4) & 3;       // stagger -> spread write banks
        const int lc = 1 + w4 * 4 + qe;
        *(unsigned*)&lds[rb + lc * 128 + ((ch ^ (lc & 7)) << 4)] = cvtpk(sa[i][0][qe], sa[i][1][qe]);
      }
    }
    if (tid < 64) {
      const int cip = tid & 31, r = tid >> 5;
      const int sl = (lr0 + r) % 6;
      *(unsigned*)&lds[sl * ROWB + RLC * 128 + (((cip >> 2) ^ (RLC & 7)) << 4) + (cip & 3) * 4] =
          cvtpk(se0, se1);
    }
  };

  // prologue: local rows 0..3
  {
    f32x4 sa[NT][2]; float se0, se1;
    stage_load(0, sa, se0, se1); stage_write(0, sa, se0, se1);
    stage_load(2, sa, se0, se1); stage_write(2, sa, se0, se1);
  }
  __syncthreads();

  for (int s = 0; s < 7; ++s) {
    // [A] issue next rows' loads (latency hides under MFMA phase)
    f32x4 sa[NT][2]; float se0, se1;
    if (s < 6) stage_load(2 * s + 4, sa, se0, se1);

    // [B] compute hpair = strip*7+s: conv rows local 2s+wr+kh, slots %6
    f32x4 acc[NF][4];
#pragma unroll
    for (int f = 0; f < NF; ++f)
#pragma unroll
      for (int nf = 0; nf < 4; ++nf) acc[f][nf] = z4;

#pragma unroll
    for (int kh = 0; kh < 3; ++kh) {
      const int rs = (2 * s + wr + kh) % 6;          // uniform per wave
#pragma unroll
      for (int kw = 0; kw < 3; ++kw) {
        const int c0 = lw + kw;                      // lc = f*16 + c0; (lc&7) f-invariant
        const int rowb = rs * ROWB + c0 * 128;
#pragma unroll
        for (int ck = 0; ck < 2; ++ck) {
          const unsigned char* bp =
              wsb + (((size_t)(((kh * 3 + kw) * 2 + ck) * 8 + wh * 4) * 64 + lane) << 4);
          bf16x8 bfr[4];
#pragma unroll
          for (int nf = 0; nf < 4; ++nf)
            bfr[nf] = *(const bf16x8*)(bp + (nf << 10));
          const int abase = rowb + ((((ck << 2) + hq) ^ (c0 & 7)) << 4);
#pragma unroll
          for (int f = 0; f < NF; ++f) {
            const bf16x8 a = *(const bf16x8*)&lds[abase + f * 2048];
#pragma unroll
            for (int nf = 0; nf < 4; ++nf)
              acc[f][nf] = __builtin_amdgcn_mfma_f32_16x16x32_bf16(a, bfr[nf], acc[f][nf], 0, 0, 0);
          }
        }
      }
    }

    // [C] convert + ds_write next rows (slots disjoint from this step's reads)
    if (s < 6) stage_write(2 * s + 4, sa, se0, se1);

    // [D] bias + relu + pools + store
    float pl0[NF][4], pl1[NF][4];
#pragma unroll
    for (int f = 0; f < NF; ++f)
#pragma unroll
      for (int nf = 0; nf < 4; ++nf) {
        const float a0 = fmaxf(acc[f][nf][0] + bb[nf], 0.f);
        const float a1 = fmaxf(acc[f][nf][1] + bb[nf], 0.f);
        const float a2 = fmaxf(acc[f][nf][2] + bb[nf], 0.f);
        const float a3 = fmaxf(acc[f][nf][3] + bb[nf], 0.f);
        pl0[f][nf] = fmaxf(a0, a1);
        pl1[f][nf] = fmaxf(a2, a3);
      }
    __syncthreads();          // staged writes visible; pb free (prev stores done)
    if (wr == 0) {
#pragma unroll
      for (int f = 0; f < NF; ++f)
#pragma unroll
        for (int nf = 0; nf < 4; ++nf) {
          const int co = wh * 64 + nf * 16 + lw;
          const int pwl = f * 8 + hq * 2;
          pb[co * PWNP + pwl] = pl0[f][nf];
          pb[co * PWNP + pwl + 1] = pl1[f][nf];
        }
    }
    __syncthreads();
    if (wr == 1) {            // vertical pool: combine with row-0 partials
#pragma unroll
      for (int f = 0; f < NF; ++f)
#pragma unroll
        for (int nf = 0; nf < 4; ++nf) {
          const int co = wh * 64 + nf * 16 + lw;
          const int pwl = f * 8 + hq * 2;
          pb[co * PWNP + pwl] = fmaxf(pl0[f][nf], pb[co * PWNP + pwl]);
          pb[co * PWNP + pwl + 1] = fmaxf(pl1[f][nf], pb[co * PWNP + pwl + 1]);
        }
    }
    __syncthreads();
    const int ph = strip * 7 + s;
#pragma unroll
    for (int i = 0; i < PWN / 8; ++i) {   // coalesced float4 stores
      const int idx = i * 256 + tid;
      const int co = idx / (PWN / 4), q = idx % (PWN / 4);
      const f32x4 v = *(const f32x4*)&pb[co * PWNP + q * 4];
      *(f32x4*)(out + (size_t)(n * 128 + co) * 3136 + ph * 56 + PWB + q * 4) = v;
    }
  }
}

__global__ __launch_bounds__(256, 2) void conv_746s(
    const float* __restrict__ x, const unsigned char* __restrict__ wsb,
    const float* __restrict__ bias, float* __restrict__ out) {
  // max LDS: NF=4 ring 6*8448=50688 + pool 128*36*4=18432 -> 69120 B (2 WGs/CU)
  __shared__ __align__(16) unsigned char lds[69120];
  const int bx = blockIdx.x;               // 512 WGs = exactly 2/CU
  const int strip = bx & 7;                // low bits -> XCD spread
  const int half = (bx >> 3) & 1;          // both halves on every XCD
  const int n = bx >> 4;
  const float* xn = x + (size_t)n * 802816;
  const int tid = threadIdx.x;
  if (half == 0)
    strip_run<4, -1, 0>(lds, xn, wsb, bias, out, n, strip, tid);   // w 0..63
  else
    strip_run<3, 63, 32>(lds, xn, wsb, bias, out, n, strip, tid);  // w 64..111
}

// ---- safety fallback if workspace is too small (should never trigger)
__global__ __launch_bounds__(256) void naive_746(
    const float* __restrict__ x, const float* __restrict__ wt,
    const float* __restrict__ bias, float* __restrict__ out) {
  int idx = blockIdx.x * 256 + threadIdx.x;
  if (idx >= 12845056) return;
  int pw = idx % 56; int t = idx / 56;
  int ph = t % 56; t /= 56;
  int co = t % 128; int n = t / 128;
  float best = 0.f;  // relu output >= 0
  for (int dh = 0; dh < 2; ++dh)
    for (int dw = 0; dw < 2; ++dw) {
      int oh = ph * 2 + dh, ow = pw * 2 + dw;
      float acc = bias[co];
      for (int ci = 0; ci < 64; ++ci) {
        const float* xp = x + ((size_t)(n * 64 + ci) * 112) * 112;
        const float* wp = wt + (co * 64 + ci) * 9;
        for (int kh = 0; kh < 3; ++kh) {
          int ih = oh + kh - 1; if (ih < 0 || ih >= 112) continue;
          for (int kw = 0; kw < 3; ++kw) {
            int iw = ow + kw - 1; if (iw < 0 || iw >= 112) continue;
            acc += xp[ih * 112 + iw] * wp[kh * 3 + kw];
          }
        }
      }
      best = fmaxf(best, fmaxf(acc, 0.f));
    }
  out[idx] = best;
}

extern "C" void kernel_launch(void* const* d_in, const int* in_sizes, int n_in,
                              void* d_out, int out_size, void* d_ws, size_t ws_size,
                              hipStream_t stream) {
  const float* x = (const float*)d_in[0];
  const float* w = (const float*)d_in[1];
  const float* b = (const float*)d_in[2];
  float* o = (float*)d_out;
  if (ws_size < (size_t)WF_BYTES) {
    naive_746<<<dim3((12845056 + 255) / 256), dim3(256), 0, stream>>>(x, w, b, o);
    return;
  }
  unsigned short* wf = (unsigned short*)d_ws;
  wxf_746<<<dim3(144), dim3(64), 0, stream>>>(w, wf);
  conv_746s<<<dim3(512), dim3(256), 0, stream>>>(x, (const unsigned char*)d_ws, b, o);
}

// Round 7
// 94.121 us; speedup vs baseline: 3.2102x; 3.2102x over previous
//
#include <hip/hip_runtime.h>

typedef __bf16 bf16x8 __attribute__((ext_vector_type(8)));
typedef float  f32x4  __attribute__((ext_vector_type(4)));
typedef unsigned u32x4 __attribute__((ext_vector_type(4)));

__device__ __forceinline__ unsigned short f2bf(float f) {
  unsigned u = __float_as_uint(f);
  u += 0x7FFFu + ((u >> 16) & 1u);   // round-to-nearest-even
  return (unsigned short)(u >> 16);
}

__device__ __forceinline__ unsigned cvtpk(float lo, float hi) {
  unsigned r;
  asm("v_cvt_pk_bf16_f32 %0, %1, %2" : "=v"(r) : "v"(lo), "v"(hi));
  return r;
}

// async global->LDS DMA, 16 B per lane, dest = wave-uniform base + lane*16
__device__ __forceinline__ void gld16(const void* g, void* l) {
  __builtin_amdgcn_global_load_lds(
      (const __attribute__((address_space(1))) void*)g,
      (__attribute__((address_space(3))) void*)l, 16, 0, 0);
}

#define WF_BYTES   147456                      // weight fragments
#define XBF_BYTES  52297728                    // 32 n * 112 h * 114 cols * 128 B
#define WS_NEED    (WF_BYTES + XBF_BYTES)

// ---- weight transform: W[128][64][3][3] f32 -> bf16 MFMA B-fragment layout
__global__ __launch_bounds__(64) void wxf_746(const float* __restrict__ w,
                                              unsigned short* __restrict__ wf) {
  const int b = blockIdx.x;            // 0..143
  const int lane = threadIdx.x;
  const int nb = b & 7, ck = (b >> 3) & 1, pos = b >> 4;
  const int kh = pos / 3, kw = pos % 3;
  const int co = nb * 16 + (lane & 15);
  const int ci0 = ck * 32 + ((lane >> 4) << 3);
  unsigned short* o = wf + ((size_t)(b * 64 + lane) << 3);
#pragma unroll
  for (int j = 0; j < 8; ++j)
    o[j] = f2bf(w[((co * 64 + ci0 + j) * 3 + kh) * 3 + kw]);
}

// ---- x prepass: fp32 NCHW -> bf16 DMA-ready rows [n][h][114 cols][64 ci]
// col 0 / col 113 = zero pads baked in; within each col's 128 B the 16-B chunk for
// ci-group ch sits at ((ch ^ (col&7))<<4)  (pre-applied XOR swizzle, m173 pattern).
__global__ __launch_bounds__(256) void xprep_746(const float* __restrict__ x,
                                                 unsigned char* __restrict__ xbf) {
  __shared__ float xt[112 * 68];       // [w][68] f32, stride 68 (16B-aligned gathers)
  const int bx = blockIdx.x;           // n*112 + h
  const int n = bx / 112, h = bx - n * 112;
  const int tid = threadIdx.x;
  const float* xp = x + (size_t)n * 802816 + (size_t)h * 112;
#pragma unroll
  for (int i = 0; i < 28; ++i) {       // 64 ci x 112 w, coalesced along w
    const int idx = i * 256 + tid;
    const int ci = idx / 112, w = idx - ci * 112;
    xt[w * 68 + ci] = xp[(size_t)ci * 12544 + w];
  }
  __syncthreads();
  unsigned char* orow = xbf + (size_t)bx * 14592;
#pragma unroll
  for (int i = 0; i < 4; ++i) {
    const int idx = i * 256 + tid;     // (col, ch): ch fastest -> coalesced stores
    if (idx < 912) {
      const int col = idx >> 3, ch = idx & 7;
      u32x4 pk = {0u, 0u, 0u, 0u};
      if (col >= 1 && col <= 112) {
        const float* s = &xt[(col - 1) * 68 + ch * 8];
        const f32x4 a = *(const f32x4*)s;
        const f32x4 b = *(const f32x4*)(s + 4);
        pk[0] = cvtpk(a[0], a[1]);
        pk[1] = cvtpk(a[2], a[3]);
        pk[2] = cvtpk(b[0], b[1]);
        pk[3] = cvtpk(b[2], b[3]);
      }
      *(u32x4*)&orow[col * 128 + ((ch ^ (col & 7)) << 4)] = pk;
    }
  }
}

// ---- conv main: DMA-staged, fused conv3x3+bias+relu+maxpool2x2, bf16 MFMA
// WG (256 thr) = (half, n, hpair). NF=4: cols 0..65 (w 0..63); NF=3: cols 64..113.
// Waves: wr = conv row, wh = cout half; acc[NF][4]. 4 WGs/CU = 16 waves.
template<int NF, int COLBASE, int PWB>
__device__ __forceinline__ void conv_half(
    unsigned char* __restrict__ lds, const unsigned char* __restrict__ xbf,
    const unsigned char* __restrict__ wsb, const float* __restrict__ bias,
    float* __restrict__ out, int n, int hpair, int tid) {
  constexpr int ROWB = (NF * 16 + 2) * 128;   // 8448 / 6400
  constexpr int NSUB = ROWB / 1024 + 1;       // 9 / 7 (last sub = 256 B, 16 lanes)
  constexpr int PWN = NF * 8, PWNP = PWN + 4;
  const int lane = tid & 63, wid = tid >> 6;
  const int wr = wid >> 1, wh = wid & 1;
  const int lw = lane & 15, hq = lane >> 4;
  const int h0 = hpair * 2;
  const f32x4 z4 = {0.f, 0.f, 0.f, 0.f};

  float bb[4];
#pragma unroll
  for (int nf = 0; nf < 4; ++nf) bb[nf] = bias[wh * 64 + nf * 16 + lw];

  // DMA stage rows h0-1..h0+2 (zero-fill out-of-image rows via ds_write)
#pragma unroll
  for (int i = 0; i < NSUB; ++i) {
    const int c = wid + 4 * i;                // 4*NSUB chunks of <=1024 B
    const int r = c / NSUB, j = c - r * NSUB;
    const int h = h0 - 1 + r;
    const int nact = (j == NSUB - 1) ? 16 : 64;
    if (lane < nact) {
      unsigned char* dst = lds + r * ROWB + j * 1024;
      if ((unsigned)h < 112u) {
        const unsigned char* src =
            xbf + ((size_t)(n * 112 + h) * 114 + COLBASE) * 128 + j * 1024 + lane * 16;
        gld16(src, dst);
      } else {
        *(f32x4*)(dst + lane * 16) = z4;
      }
    }
  }
  __syncthreads();   // drains vmcnt (DMA) + lgkm

  // implicit GEMM: M = NF*16 w, N = 64 couts/wave (nf=4), K = 576
  f32x4 acc[NF][4];
#pragma unroll
  for (int f = 0; f < NF; ++f)
#pragma unroll
    for (int nf = 0; nf < 4; ++nf) acc[f][nf] = z4;

#pragma unroll
  for (int kh = 0; kh < 3; ++kh) {
#pragma unroll
    for (int kw = 0; kw < 3; ++kw) {
      const int c0 = lw + kw;                 // local col = f*16 + c0; (c0&7) f-invariant
      const int rowb = (wr + kh) * ROWB + c0 * 128;
#pragma unroll
      for (int ck = 0; ck < 2; ++ck) {
        const unsigned char* bp =
            wsb + (((size_t)(((kh * 3 + kw) * 2 + ck) * 8 + wh * 4) * 64 + lane) << 4);
        bf16x8 bfr[4];
#pragma unroll
        for (int nf = 0; nf < 4; ++nf)
          bfr[nf] = *(const bf16x8*)(bp + (nf << 10));
        const int abase = rowb + ((((ck << 2) + hq) ^ (c0 & 7)) << 4);
#pragma unroll
        for (int f = 0; f < NF; ++f) {
          const bf16x8 a = *(const bf16x8*)&lds[abase + f * 2048];
#pragma unroll
          for (int nf = 0; nf < 4; ++nf)
            acc[f][nf] = __builtin_amdgcn_mfma_f32_16x16x32_bf16(a, bfr[nf], acc[f][nf], 0, 0, 0);
        }
      }
    }
  }

  // bias + relu + horizontal pool (in-lane: acc regs are 4 consecutive w)
  __syncthreads();   // x tile dead; reuse LDS as pool buffer [128 co][PWNP]
  float pl0[NF][4], pl1[NF][4];
#pragma unroll
  for (int f = 0; f < NF; ++f)
#pragma unroll
    for (int nf = 0; nf < 4; ++nf) {
      const float a0 = fmaxf(acc[f][nf][0] + bb[nf], 0.f);
      const float a1 = fmaxf(acc[f][nf][1] + bb[nf], 0.f);
      const float a2 = fmaxf(acc[f][nf][2] + bb[nf], 0.f);
      const float a3 = fmaxf(acc[f][nf][3] + bb[nf], 0.f);
      pl0[f][nf] = fmaxf(a0, a1);
      pl1[f][nf] = fmaxf(a2, a3);
    }
  float* pb = (float*)lds;
  if (wr == 0) {
#pragma unroll
    for (int f = 0; f < NF; ++f)
#pragma unroll
      for (int nf = 0; nf < 4; ++nf) {
        const int co = wh * 64 + nf * 16 + lw;
        const int pwl = f * 8 + hq * 2;
        pb[co * PWNP + pwl] = pl0[f][nf];
        pb[co * PWNP + pwl + 1] = pl1[f][nf];
      }
  }
  __syncthreads();
  if (wr == 1) {   // vertical pool: combine with row-0 partials
#pragma unroll
    for (int f = 0; f < NF; ++f)
#pragma unroll
      for (int nf = 0; nf < 4; ++nf) {
        const int co = wh * 64 + nf * 16 + lw;
        const int pwl = f * 8 + hq * 2;
        pb[co * PWNP + pwl] = fmaxf(pl0[f][nf], pb[co * PWNP + pwl]);
        pb[co * PWNP + pwl + 1] = fmaxf(pl1[f][nf], pb[co * PWNP + pwl + 1]);
      }
  }
  __syncthreads();
  constexpr int NQ4 = PWN / 4;
#pragma unroll
  for (int i = 0; i < PWN / 8; ++i) {   // coalesced float4 stores
    const int idx = i * 256 + tid;
    const int co = idx / NQ4, q = idx % NQ4;
    const f32x4 v = *(const f32x4*)&pb[co * PWNP + q * 4];
    *(f32x4*)(out + (size_t)(n * 128 + co) * 3136 + hpair * 56 + PWB + q * 4) = v;
  }
}

__global__ __launch_bounds__(256, 4) void conv_746d(
    const unsigned char* __restrict__ xbf, const unsigned char* __restrict__ wsb,
    const float* __restrict__ bias, float* __restrict__ out) {
  __shared__ __align__(16) unsigned char lds[33792];   // max (NF=4) tile; pool reuses it
  const int bx = blockIdx.x;            // 3584 = 2 halves x 32 n x 56 hpair
  const int half = bx & 1;              // adjacent blocks share rows -> L2 locality
  const int rest = bx >> 1;
  const int n = rest / 56, hpair = rest - n * 56;
  if (half == 0)
    conv_half<4, 0, 0>(lds, xbf, wsb, bias, out, n, hpair, threadIdx.x);
  else
    conv_half<3, 64, 32>(lds, xbf, wsb, bias, out, n, hpair, threadIdx.x);
}

// ================= fallback tier 1: in-kernel convert (R5 path, needs 147 KB ws) ====
template<int NF, int WLO, int PWB>
__global__ __launch_bounds__(256, 4) void conv_746t(
    const float* __restrict__ x, const unsigned char* __restrict__ wsb,
    const float* __restrict__ bias, float* __restrict__ out) {
  constexpr int NCOLS = NF * 16 + 2;
  constexpr int ROWB  = NCOLS * 128;
  constexpr int NQ    = NF * 4;
  constexpr int PWN   = NF * 8;
  constexpr int PWNP  = PWN + 4;
  __shared__ __align__(16) unsigned char lds[4 * ROWB];
  const int bx = blockIdx.x;
  const int n = bx / 56, hpair = bx % 56, h0 = hpair * 2;
  const int tid = threadIdx.x;
  const int lane = tid & 63, wid = tid >> 6;
  const int wr = wid >> 1, wh = wid & 1;
  const int lw = lane & 15, hq = lane >> 4;
  float bb[4];
#pragma unroll
  for (int nf = 0; nf < 4; ++nf) bb[nf] = bias[wh * 64 + nf * 16 + lw];
  const f32x4 z4 = {0.f, 0.f, 0.f, 0.f};
  if (hpair == 0)
    for (int i = tid * 16; i < ROWB; i += 4096) *(f32x4*)&lds[i] = z4;
  if (hpair == 55)
    for (int i = tid * 16; i < ROWB; i += 4096) *(f32x4*)&lds[3 * ROWB + i] = z4;
  const float* xn = x + (size_t)n * 802816;
  {
    const int cs = tid & 1, r = (tid >> 1) & 3, cip = tid >> 3;
    const int lc = cs ? (NCOLS - 1) : 0;
    const int w = WLO + lc;
    const int h = h0 - 1 + r;
    if ((unsigned)h < 112u) {
      unsigned pk = 0;
      if ((unsigned)w < 112u) {
        const float* p = xn + (size_t)(cip * 2) * 12544 + h * 112 + w;
        pk = cvtpk(p[0], p[12544]);
      }
      *(unsigned*)&lds[r * ROWB + lc * 128 + (((cip >> 2) ^ (lc & 7)) << 4) + (cip & 3) * 4] = pk;
    }
  }
#pragma unroll
  for (int i = 0; i < NQ / 2; ++i) {
    const int idx = i * 256 + tid;
    const int w4 = idx % NQ;
    const int t = idx / NQ;
    const int cip = t & 31, r = t >> 5;
    const int h = h0 - 1 + r;
    if ((unsigned)h < 112u) {
      const float* p = xn + (size_t)(cip * 2) * 12544 + h * 112 + (WLO + 1 + w4 * 4);
      const f32x4 a0 = *(const f32x4*)p;
      const f32x4 a1 = *(const f32x4*)(p + 12544);
      const int rb = r * ROWB + (cip & 3) * 4;
      const int ch = cip >> 2;
#pragma unroll
      for (int q = 0; q < 4; ++q) {
        const int lc = 1 + w4 * 4 + q;
        *(unsigned*)&lds[rb + lc * 128 + ((ch ^ (lc & 7)) << 4)] = cvtpk(a0[q], a1[q]);
      }
    }
  }
  __syncthreads();
  f32x4 acc[NF][4];
#pragma unroll
  for (int f = 0; f < NF; ++f)
#pragma unroll
    for (int nf = 0; nf < 4; ++nf) acc[f][nf] = z4;
#pragma unroll
  for (int kh = 0; kh < 3; ++kh) {
#pragma unroll
    for (int kw = 0; kw < 3; ++kw) {
      const int c0 = lw + kw;
      const int rowb = (wr + kh) * ROWB + c0 * 128;
#pragma unroll
      for (int ck = 0; ck < 2; ++ck) {
        const unsigned char* bp =
            wsb + (((size_t)(((kh * 3 + kw) * 2 + ck) * 8 + wh * 4) * 64 + lane) << 4);
        bf16x8 bfr[4];
#pragma unroll
        for (int nf = 0; nf < 4; ++nf)
          bfr[nf] = *(const bf16x8*)(bp + (nf << 10));
        const int abase = rowb + ((((ck << 2) + hq) ^ (c0 & 7)) << 4);
#pragma unroll
        for (int f = 0; f < NF; ++f) {
          const bf16x8 a = *(const bf16x8*)&lds[abase + f * 2048];
#pragma unroll
          for (int nf = 0; nf < 4; ++nf)
            acc[f][nf] = __builtin_amdgcn_mfma_f32_16x16x32_bf16(a, bfr[nf], acc[f][nf], 0, 0, 0);
        }
      }
    }
  }
  __syncthreads();
  float pl0[NF][4], pl1[NF][4];
#pragma unroll
  for (int f = 0; f < NF; ++f)
#pragma unroll
    for (int nf = 0; nf < 4; ++nf) {
      const float a0 = fmaxf(acc[f][nf][0] + bb[nf], 0.f);
      const float a1 = fmaxf(acc[f][nf][1] + bb[nf], 0.f);
      const float a2 = fmaxf(acc[f][nf][2] + bb[nf], 0.f);
      const float a3 = fmaxf(acc[f][nf][3] + bb[nf], 0.f);
      pl0[f][nf] = fmaxf(a0, a1);
      pl1[f][nf] = fmaxf(a2, a3);
    }
  float* pb = (float*)lds;
  if (wr == 0) {
#pragma unroll
    for (int f = 0; f < NF; ++f)
#pragma unroll
      for (int nf = 0; nf < 4; ++nf) {
        const int co = wh * 64 + nf * 16 + lw;
        const int pwl = f * 8 + hq * 2;
        pb[co * PWNP + pwl] = pl0[f][nf];
        pb[co * PWNP + pwl + 1] = pl1[f][nf];
      }
  }
  __syncthreads();
  if (wr == 1) {
#pragma unroll
    for (int f = 0; f < NF; ++f)
#pragma unroll
      for (int nf = 0; nf < 4; ++nf) {
        const int co = wh * 64 + nf * 16 + lw;
        const int pwl = f * 8 + hq * 2;
        pb[co * PWNP + pwl] = fmaxf(pl0[f][nf], pb[co * PWNP + pwl]);
        pb[co * PWNP + pwl + 1] = fmaxf(pl1[f][nf], pb[co * PWNP + pwl + 1]);
      }
  }
  __syncthreads();
  constexpr int NQ4 = PWN / 4;
#pragma unroll
  for (int i = 0; i < PWN / 8; ++i) {
    const int idx = i * 256 + tid;
    const int co = idx / NQ4, q = idx % NQ4;
    const f32x4 v = *(const f32x4*)&pb[co * PWNP + q * 4];
    *(f32x4*)(out + (size_t)(n * 128 + co) * 3136 + hpair * 56 + PWB + q * 4) = v;
  }
}

// ---- fallback tier 2: naive (tiny ws)
__global__ __launch_bounds__(256) void naive_746(
    const float* __restrict__ x, const float* __restrict__ wt,
    const float* __restrict__ bias, float* __restrict__ out) {
  int idx = blockIdx.x * 256 + threadIdx.x;
  if (idx >= 12845056) return;
  int pw = idx % 56; int t = idx / 56;
  int ph = t % 56; t /= 56;
  int co = t % 128; int n = t / 128;
  float best = 0.f;
  for (int dh = 0; dh < 2; ++dh)
    for (int dw = 0; dw < 2; ++dw) {
      int oh = ph * 2 + dh, ow = pw * 2 + dw;
      float acc = bias[co];
      for (int ci = 0; ci < 64; ++ci) {
        const float* xp = x + ((size_t)(n * 64 + ci) * 112) * 112;
        const float* wp = wt + (co * 64 + ci) * 9;
        for (int kh = 0; kh < 3; ++kh) {
          int ih = oh + kh - 1; if (ih < 0 || ih >= 112) continue;
          for (int kw = 0; kw < 3; ++kw) {
            int iw = ow + kw - 1; if (iw < 0 || iw >= 112) continue;
            acc += xp[ih * 112 + iw] * wp[kh * 3 + kw];
          }
        }
      }
      best = fmaxf(best, fmaxf(acc, 0.f));
    }
  out[idx] = best;
}

extern "C" void kernel_launch(void* const* d_in, const int* in_sizes, int n_in,
                              void* d_out, int out_size, void* d_ws, size_t ws_size,
                              hipStream_t stream) {
  const float* x = (const float*)d_in[0];
  const float* w = (const float*)d_in[1];
  const float* b = (const float*)d_in[2];
  float* o = (float*)d_out;
  if (ws_size < (size_t)WF_BYTES) {
    naive_746<<<dim3((12845056 + 255) / 256), dim3(256), 0, stream>>>(x, w, b, o);
    return;
  }
  unsigned short* wf = (unsigned short*)d_ws;
  wxf_746<<<dim3(144), dim3(64), 0, stream>>>(w, wf);
  if (ws_size < (size_t)WS_NEED) {     // tier-1 fallback: in-kernel convert (R5)
    conv_746t<4, -1, 0><<<dim3(1792), dim3(256), 0, stream>>>(x, (const unsigned char*)d_ws, b, o);
    conv_746t<3, 63, 32><<<dim3(1792), dim3(256), 0, stream>>>(x, (const unsigned char*)d_ws, b, o);
    return;
  }
  unsigned char* xbf = (unsigned char*)d_ws + WF_BYTES;
  xprep_746<<<dim3(3584), dim3(256), 0, stream>>>(x, xbf);
  conv_746d<<<dim3(3584), dim3(256), 0, stream>>>(xbf, (const unsigned char*)d_ws, b, o);
}